// Round 1
// baseline (518.664 us; speedup 1.0000x reference)
//
#include <hip/hip_runtime.h>
#include <hip/hip_bf16.h>
#include <math.h>

// Problem constants: B=32, S=16, D=64, E=768
#define EPSF 1e-12f

__device__ __forceinline__ float gelu_exact(float x) {
    return 0.5f * x * (1.0f + erff(x * 0.70710678118f));
}

// ---------------------------------------------------------------------------
// Norms: per doc row (2048) -> l2 scale; per seg row (512) -> l2 scale, mean,
// centered-norm scale (for Pearson z).
// ---------------------------------------------------------------------------
__global__ __launch_bounds__(64) void k_norms(
    const float* __restrict__ doc, const float* __restrict__ seg,
    float* __restrict__ dscale, float* __restrict__ sscale,
    float* __restrict__ smean, float* __restrict__ cscale)
{
    int row = blockIdx.x;      // 0..2559
    int lane = threadIdx.x;    // 0..63
    const float* src = (row < 2048) ? (doc + (size_t)row * 768)
                                    : (seg + (size_t)(row - 2048) * 768);
    float ss = 0.f, sm = 0.f;
    #pragma unroll
    for (int i = 0; i < 12; ++i) {
        float x = src[lane + 64 * i];
        ss += x * x; sm += x;
    }
    #pragma unroll
    for (int off = 32; off > 0; off >>= 1) {
        ss += __shfl_down(ss, off);
        sm += __shfl_down(sm, off);
    }
    if (lane == 0) {
        if (row < 2048) {
            dscale[row] = rsqrtf(fmaxf(ss, EPSF));
        } else {
            int r = row - 2048;
            sscale[r] = rsqrtf(fmaxf(ss, EPSF));
            float mean = sm * (1.0f / 768.0f);
            smean[r] = mean;
            float css = ss - sm * mean;     // sum((x-mean)^2)
            cscale[r] = rsqrtf(fmaxf(css, EPSF));
        }
    }
}

// ---------------------------------------------------------------------------
// Layer-1 GEMM: C[M,768] = A[M,768] @ W1[wrow_off:wrow_off+768, 0:768] (+bias)
// Classic 64x64 tile, BK=16, 256 threads, 4x4 microtile.
// ---------------------------------------------------------------------------
__global__ __launch_bounds__(256) void k_gemm64(
    const float* __restrict__ A, const float* __restrict__ W,
    const float* __restrict__ bias, float* __restrict__ C,
    int K, int N, int wrow_off)
{
    __shared__ float sA[16][68];
    __shared__ float sB[16][68];
    int t = threadIdx.x;
    int tx = t & 15, ty = t >> 4;
    int by = blockIdx.x, bx = blockIdx.y;   // (M/64, N/64)
    float acc[4][4];
    #pragma unroll
    for (int i = 0; i < 4; ++i)
        #pragma unroll
        for (int j = 0; j < 4; ++j) acc[i][j] = 0.f;

    int am = t >> 2;             // 0..63 (A row in tile)
    int ak0 = (t & 3) * 4;       // 0,4,8,12
    int bk = t >> 4;             // 0..15 (W row in tile)
    int bc0 = (t & 15) * 4;      // col in tile
    const float* Abase = A + (size_t)(by * 64 + am) * K;

    for (int kt = 0; kt < K; kt += 16) {
        float4 av = *(const float4*)(Abase + kt + ak0);
        float4 bv = *(const float4*)(W + (size_t)(wrow_off + kt + bk) * N + bx * 64 + bc0);
        __syncthreads();
        sA[ak0 + 0][am] = av.x; sA[ak0 + 1][am] = av.y;
        sA[ak0 + 2][am] = av.z; sA[ak0 + 3][am] = av.w;
        *(float4*)&sB[bk][bc0] = bv;
        __syncthreads();
        #pragma unroll
        for (int kk = 0; kk < 16; ++kk) {
            float a4[4], b4[4];
            *(float4*)a4 = *(const float4*)&sA[kk][ty * 4];
            *(float4*)b4 = *(const float4*)&sB[kk][tx * 4];
            #pragma unroll
            for (int i = 0; i < 4; ++i)
                #pragma unroll
                for (int j = 0; j < 4; ++j)
                    acc[i][j] += a4[i] * b4[j];
        }
    }
    int row0 = by * 64 + ty * 4, col0 = bx * 64 + tx * 4;
    float4 bb = bias ? *(const float4*)(bias + col0) : make_float4(0.f, 0.f, 0.f, 0.f);
    #pragma unroll
    for (int i = 0; i < 4; ++i) {
        float4 o;
        o.x = acc[i][0] + bb.x; o.y = acc[i][1] + bb.y;
        o.z = acc[i][2] + bb.z; o.w = acc[i][3] + bb.w;
        *(float4*)(C + (size_t)(row0 + i) * N + col0) = o;
    }
}

// ---------------------------------------------------------------------------
// Fused pred kernel: one block per (b,s).
// h1[d,k] = gelu(Xdoc[b,d,k] + Xseg[b,s,k])      (Xseg includes b1)
// h2 = h1 @ W2 ; h3 = gelu(h2+b2) @ W3 + b3 ; sig = sigmoid(h3)
// pred[b,s] = seg_scale * max_d (d<nd ? sig : 0)
// 32-row passes (2), BK=32, W2 k-chunk staged in LDS.
// Thread (rg=t/32, cg=t%32) owns rows rg*4..+3, cols cg*12..+11.
// ---------------------------------------------------------------------------
__global__ __launch_bounds__(256) void k_fused(
    const float* __restrict__ Xdoc, const float* __restrict__ Xseg,
    const float* __restrict__ W2, const float* __restrict__ b2,
    const float* __restrict__ W3, const float* __restrict__ b3,
    const int* __restrict__ nd, const int* __restrict__ ns,
    float* __restrict__ out_pred, float* __restrict__ predv)
{
    __shared__ float sXseg[768];
    __shared__ float sW2[32 * 384];
    __shared__ float sH1T[32][36];   // [kk][row], padded to 36 (16B-aligned rows)
    __shared__ float sRed[32][33];
    __shared__ float sSig[64];

    int bs = blockIdx.x;        // 0..511
    int b = bs >> 4;
    int t = threadIdx.x;

    if (t < 192) ((float4*)sXseg)[t] = ((const float4*)(Xseg + (size_t)bs * 768))[t];

    int rg = t >> 5;            // 0..7
    int cg = t & 31;            // 0..31
    int hr = t >> 3;            // 0..31 (h1 staging row)
    int hk0 = (t & 7) * 4;      // 0..28 (h1 staging k)
    const int ndb = nd[b];
    __syncthreads();

    for (int pass = 0; pass < 2; ++pass) {
        float acc[4][12];
        #pragma unroll
        for (int i = 0; i < 4; ++i)
            #pragma unroll
            for (int c = 0; c < 12; ++c) acc[i][c] = 0.f;

        const float* xdrow = Xdoc + (size_t)(b * 64 + pass * 32 + hr) * 768;

        for (int kt = 0; kt < 24; ++kt) {
            // prefetch globals into regs before the barrier
            float4 w2buf[12];
            const float4* gW2 = (const float4*)(W2 + (size_t)kt * 32 * 384);
            #pragma unroll
            for (int i = 0; i < 12; ++i) w2buf[i] = gW2[t + i * 256];
            float4 xd = *(const float4*)(xdrow + kt * 32 + hk0);
            __syncthreads();   // previous compute done before overwrite
            #pragma unroll
            for (int i = 0; i < 12; ++i) ((float4*)sW2)[t + i * 256] = w2buf[i];
            {
                float4 xs = *(const float4*)&sXseg[kt * 32 + hk0];
                sH1T[hk0 + 0][hr] = gelu_exact(xd.x + xs.x);
                sH1T[hk0 + 1][hr] = gelu_exact(xd.y + xs.y);
                sH1T[hk0 + 2][hr] = gelu_exact(xd.z + xs.z);
                sH1T[hk0 + 3][hr] = gelu_exact(xd.w + xs.w);
            }
            __syncthreads();
            #pragma unroll 4
            for (int kk = 0; kk < 32; ++kk) {
                float a4[4], bv[12];
                *(float4*)a4 = *(const float4*)&sH1T[kk][rg * 4];
                const float* wrow = sW2 + kk * 384 + cg * 12;
                *(float4*)&bv[0] = *(const float4*)(wrow);
                *(float4*)&bv[4] = *(const float4*)(wrow + 4);
                *(float4*)&bv[8] = *(const float4*)(wrow + 8);
                #pragma unroll
                for (int i = 0; i < 4; ++i)
                    #pragma unroll
                    for (int c = 0; c < 12; ++c)
                        acc[i][c] += a4[i] * bv[c];
            }
        }
        // epilogue: gelu(h2+b2)*W3, reduce across cg
        float p[4];
        #pragma unroll
        for (int i = 0; i < 4; ++i) {
            float sum = 0.f;
            #pragma unroll
            for (int c = 0; c < 12; ++c) {
                int j = cg * 12 + c;
                sum += gelu_exact(acc[i][c] + b2[j]) * W3[j];
            }
            p[i] = sum;
        }
        __syncthreads();
        #pragma unroll
        for (int i = 0; i < 4; ++i) sRed[rg * 4 + i][cg] = p[i];
        __syncthreads();
        if (t < 32) {
            float h3 = b3[0];
            #pragma unroll
            for (int c = 0; c < 32; ++c) h3 += sRed[t][c];
            float sig = 1.0f / (1.0f + __expf(-h3));
            int d = pass * 32 + t;
            sSig[d] = (d < ndb) ? sig : 0.f;
        }
        __syncthreads();
    }

    if (t == 0) {
        float m = 0.f;
        #pragma unroll
        for (int d = 0; d < 64; ++d) m = fmaxf(m, sSig[d]);
        float scale = (ns[b] > 10) ? 1.0f : 100.0f;
        float pv = scale * m;
        out_pred[bs] = pv;
        predv[bs] = pv;
    }
}

// ---------------------------------------------------------------------------
// Cosine prior per (b,s): doc_cos = max_d mask*(1-cos)/2 ; diff = |dc-pred|*segmask
// ---------------------------------------------------------------------------
__global__ __launch_bounds__(256) void k_cos(
    const float* __restrict__ doc, const float* __restrict__ seg,
    const float* __restrict__ dscale, const float* __restrict__ sscale,
    const int* __restrict__ nd, const int* __restrict__ ns,
    const float* __restrict__ predv, float* __restrict__ diffs)
{
    __shared__ float sS[768];
    __shared__ float wm[4];
    int bs = blockIdx.x;
    int b = bs >> 4, s = bs & 15;
    int t = threadIdx.x;
    int lane = t & 63, w = t >> 6;
    if (t < 192) ((float4*)sS)[t] = ((const float4*)(seg + (size_t)bs * 768))[t];
    __syncthreads();
    const int ndb = nd[b];
    const float ssc = sscale[bs];
    float wmax = 0.f;
    for (int d = w; d < 64; d += 4) {
        const float* dp = doc + (size_t)(b * 64 + d) * 768;
        float part = 0.f;
        #pragma unroll
        for (int i = 0; i < 12; ++i) part += sS[lane + 64 * i] * dp[lane + 64 * i];
        #pragma unroll
        for (int off = 32; off > 0; off >>= 1) part += __shfl_down(part, off);
        if (lane == 0) {
            float cosv = part * ssc * dscale[b * 64 + d];
            float sim = (d < ndb) ? (1.0f - cosv) * 0.5f : 0.f;
            wmax = fmaxf(wmax, sim);
        }
    }
    if (lane == 0) wm[w] = wmax;
    __syncthreads();
    if (t == 0) {
        float dc = fmaxf(fmaxf(wm[0], wm[1]), fmaxf(wm[2], wm[3]));
        float diff = fabsf(dc - predv[bs]);
        diffs[bs] = (s < ns[b]) ? diff : 0.f;
    }
}

// ---------------------------------------------------------------------------
// Correlation prior per b: z = centered-normalized seg rows; R=(1+z.z)/2;
// term = |t1-R|*|t2-R|*mask ; corrb[b] = sum(term)/ns
// thread t -> pair (s=t/16, tt=t%16); 256 threads = all 256 pairs.
// ---------------------------------------------------------------------------
__global__ __launch_bounds__(256) void k_corr(
    const float* __restrict__ seg, const float* __restrict__ smean,
    const float* __restrict__ cscale, const int* __restrict__ ns,
    const float* __restrict__ predv, float* __restrict__ corrb)
{
    __shared__ float sZ[16][772];   // +4 pad, rows stay 16B-aligned
    __shared__ float wsum[4];
    int b = blockIdx.x;
    int t = threadIdx.x;
    for (int i = t; i < 16 * 768; i += 256) {
        int s = i / 768; int e = i - s * 768;
        sZ[s][e] = (seg[((size_t)b * 16 + s) * 768 + e] - smean[b * 16 + s]) * cscale[b * 16 + s];
    }
    __syncthreads();
    int s = t >> 4, tt = t & 15;
    const float4* z1 = (const float4*)&sZ[s][0];
    const float4* z2 = (const float4*)&sZ[tt][0];
    float dot = 0.f;
    #pragma unroll 4
    for (int e = 0; e < 192; ++e) {
        float4 a = z1[e], c = z2[e];
        dot += a.x * c.x + a.y * c.y + a.z * c.z + a.w * c.w;
    }
    float R = 0.5f * (1.0f + dot);
    int nsb = ns[b];
    float ps = predv[b * 16 + s], pt = predv[b * 16 + tt];
    float t1 = (1.f - ps) * (1.f - pt), t2 = ps * pt;
    float term = (s < nsb && tt < nsb) ? fabsf(t1 - R) * fabsf(t2 - R) : 0.f;
    #pragma unroll
    for (int off = 32; off > 0; off >>= 1) term += __shfl_down(term, off);
    int lane = t & 63, w = t >> 6;
    if (lane == 0) wsum[w] = term;
    __syncthreads();
    if (t == 0) corrb[b] = (wsum[0] + wsum[1] + wsum[2] + wsum[3]) / (float)nsb;
}

// ---------------------------------------------------------------------------
// Finalize: passthrough copies + scalar reductions.
// out layout: [0,32) tagg | [32,544) tis | [544,1056) pred | [1056,1088) ns |
//             [1088] cos_prior | [1089] corr_prior
// ---------------------------------------------------------------------------
__global__ __launch_bounds__(256) void k_final(
    const float* __restrict__ tagg, const float* __restrict__ tis,
    const int* __restrict__ ns, const float* __restrict__ diffs,
    const float* __restrict__ corrb, float* __restrict__ out)
{
    int t = threadIdx.x;
    if (t < 32) out[t] = tagg[t];
    out[32 + t] = tis[t];
    out[32 + 256 + t] = tis[256 + t];
    if (t < 32) out[1056 + t] = (float)ns[t];
    float l1 = 0.f, l2 = 0.f;
    if (t < 32) {
        float sb = 0.f;
        #pragma unroll
        for (int s2 = 0; s2 < 16; ++s2) sb += diffs[t * 16 + s2];
        l1 = sb / (float)ns[t];
        l2 = corrb[t];
    }
    #pragma unroll
    for (int off = 16; off > 0; off >>= 1) {
        l1 += __shfl_down(l1, off);
        l2 += __shfl_down(l2, off);
    }
    if (t == 0) { out[1088] = l1 * (1.0f / 32.0f); out[1089] = l2 * (1.0f / 32.0f); }
}

// ---------------------------------------------------------------------------
extern "C" void kernel_launch(void* const* d_in, const int* in_sizes, int n_in,
                              void* d_out, int out_size, void* d_ws, size_t ws_size,
                              hipStream_t stream)
{
    const float* doc  = (const float*)d_in[0];   // [32,64,768]
    const float* seg  = (const float*)d_in[1];   // [32,16,768]
    const int*   nd   = (const int*)d_in[2];     // [32]
    const int*   ns   = (const int*)d_in[3];     // [32]
    const float* tagg = (const float*)d_in[4];   // [32]
    const float* tis  = (const float*)d_in[5];   // [32,16]
    const float* W1   = (const float*)d_in[6];   // [1536,768]
    const float* b1   = (const float*)d_in[7];   // [768]
    const float* W2   = (const float*)d_in[8];   // [768,384]
    const float* b2   = (const float*)d_in[9];   // [384]
    const float* W3   = (const float*)d_in[10];  // [384,1]
    const float* b3   = (const float*)d_in[11];  // [1]
    float* out = (float*)d_out;

    float* ws     = (float*)d_ws;
    float* Xdoc   = ws;                      // 2048*768
    float* Xseg   = Xdoc + 2048 * 768;       // 512*768
    float* dscale = Xseg + 512 * 768;        // 2048
    float* sscale = dscale + 2048;           // 512
    float* smean  = sscale + 512;            // 512
    float* cscale = smean + 512;             // 512
    float* predv  = cscale + 512;            // 512
    float* diffs  = predv + 512;             // 512
    float* corrb  = diffs + 512;             // 32

    k_norms<<<2560, 64, 0, stream>>>(doc, seg, dscale, sscale, smean, cscale);
    k_gemm64<<<dim3(32, 12), 256, 0, stream>>>(doc, W1, nullptr, Xdoc, 768, 768, 0);
    k_gemm64<<<dim3(8, 12), 256, 0, stream>>>(seg, W1, b1, Xseg, 768, 768, 768);
    k_fused<<<512, 256, 0, stream>>>(Xdoc, Xseg, W2, b2, W3, b3, nd, ns, out + 544, predv);
    k_cos<<<512, 256, 0, stream>>>(doc, seg, dscale, sscale, nd, ns, predv, diffs);
    k_corr<<<32, 256, 0, stream>>>(seg, smean, cscale, ns, predv, corrb);
    k_final<<<1, 256, 0, stream>>>(tagg, tis, ns, diffs, corrb, out);
}

// Round 2
// 173.848 us; speedup vs baseline: 2.9834x; 2.9834x over previous
//
#include <hip/hip_runtime.h>
#include <hip/hip_bf16.h>
#include <math.h>

// Problem constants: B=32, S=16, D=64, E=768
#define EPSF 1e-12f

typedef short bf16x8 __attribute__((ext_vector_type(8)));
typedef float f32x4  __attribute__((ext_vector_type(4)));

__device__ __forceinline__ float gelu_exact(float x) {
    return 0.5f * x * (1.0f + erff(x * 0.70710678118f));
}
__device__ __forceinline__ float bf2f(unsigned short u) {
    return __uint_as_float(((unsigned int)u) << 16);
}
__device__ __forceinline__ unsigned short f2bf(float f) {
    unsigned int u = __float_as_uint(f);
    u += 0x7FFFu + ((u >> 16) & 1u);     // RNE
    return (unsigned short)(u >> 16);
}
__device__ __forceinline__ void gload_lds16(const void* g, void* l) {
    __builtin_amdgcn_global_load_lds(
        (const __attribute__((address_space(1))) void*)g,
        (__attribute__((address_space(3))) void*)l, 16, 0, 0);
}

// ---------------------------------------------------------------------------
// Norms (unchanged): per doc row l2 scale; per seg row l2 scale, mean, cnorm.
// ---------------------------------------------------------------------------
__global__ __launch_bounds__(64) void k_norms(
    const float* __restrict__ doc, const float* __restrict__ seg,
    float* __restrict__ dscale, float* __restrict__ sscale,
    float* __restrict__ smean, float* __restrict__ cscale)
{
    int row = blockIdx.x;
    int lane = threadIdx.x;
    const float* src = (row < 2048) ? (doc + (size_t)row * 768)
                                    : (seg + (size_t)(row - 2048) * 768);
    float ss = 0.f, sm = 0.f;
    #pragma unroll
    for (int i = 0; i < 12; ++i) {
        float x = src[lane + 64 * i];
        ss += x * x; sm += x;
    }
    #pragma unroll
    for (int off = 32; off > 0; off >>= 1) {
        ss += __shfl_down(ss, off);
        sm += __shfl_down(sm, off);
    }
    if (lane == 0) {
        if (row < 2048) {
            dscale[row] = rsqrtf(fmaxf(ss, EPSF));
        } else {
            int r = row - 2048;
            sscale[r] = rsqrtf(fmaxf(ss, EPSF));
            float mean = sm * (1.0f / 768.0f);
            smean[r] = mean;
            cscale[r] = rsqrtf(fmaxf(ss - sm * mean, EPSF));
        }
    }
}

// ---------------------------------------------------------------------------
// fp32 -> bf16 elementwise convert (vectorized)
// ---------------------------------------------------------------------------
__global__ __launch_bounds__(256) void k_cvt_bf16(
    const float* __restrict__ in, unsigned short* __restrict__ out, int n4)
{
    int i = blockIdx.x * 256 + threadIdx.x;
    if (i < n4) {
        float4 v = ((const float4*)in)[i];
        ushort4 o;
        o.x = f2bf(v.x); o.y = f2bf(v.y); o.z = f2bf(v.z); o.w = f2bf(v.w);
        *(ushort4*)(out + (size_t)i * 4) = o;
    }
}

// ---------------------------------------------------------------------------
// Transpose + convert: in fp32 [R][C] -> out bf16 [C][R]. 64x64 tiles.
// ---------------------------------------------------------------------------
__global__ __launch_bounds__(256) void k_transpose_cvt(
    const float* __restrict__ in, unsigned short* __restrict__ out, int R, int C)
{
    __shared__ float sT[64][65];
    int c0 = blockIdx.x * 64, r0 = blockIdx.y * 64;
    int t = threadIdx.x;
    int tr = t >> 2, tc4 = (t & 3) * 16;
    #pragma unroll
    for (int i = 0; i < 4; ++i) {
        float4 v = *(const float4*)(in + (size_t)(r0 + tr) * C + c0 + tc4 + i * 4);
        sT[tr][tc4 + i * 4 + 0] = v.x; sT[tr][tc4 + i * 4 + 1] = v.y;
        sT[tr][tc4 + i * 4 + 2] = v.z; sT[tr][tc4 + i * 4 + 3] = v.w;
    }
    __syncthreads();
    union { uint4 v; unsigned short u[8]; } o0, o1;
    #pragma unroll
    for (int i = 0; i < 8; ++i) o0.u[i] = f2bf(sT[tc4 + i][tr]);
    #pragma unroll
    for (int i = 0; i < 8; ++i) o1.u[i] = f2bf(sT[tc4 + 8 + i][tr]);
    *(uint4*)(out + (size_t)(c0 + tr) * R + r0 + tc4) = o0.v;
    *(uint4*)(out + (size_t)(c0 + tr) * R + r0 + tc4 + 8) = o1.v;
}

// ---------------------------------------------------------------------------
// Layer-1 MFMA GEMM: C_bf16[M][768] = A_bf16[M][768] @ W1T_bf16[:, koff..]^T
// BM=64, BN=128, BK=64. 4 waves; wave w -> n-tiles {2w, 2w+1} of the 8.
// LDS linear dest via global_load_lds; XOR-swizzle via pre-swizzled source.
// ---------------------------------------------------------------------------
__global__ __launch_bounds__(256) void k_l1(
    const unsigned short* __restrict__ A_bf, const unsigned short* __restrict__ W1T_bf,
    const float* __restrict__ bias, unsigned short* __restrict__ C_bf, int koff_bytes)
{
    __shared__ unsigned short sA[64 * 64];    // 8KB  (rows 128B, swizzled)
    __shared__ unsigned short sB[128 * 64];   // 16KB
    int m0 = blockIdx.x * 64, n0 = blockIdx.y * 128;
    int t = threadIdx.x, w = t >> 6, l = t & 63;
    int lr = l >> 3, lc = l & 7;
    int xw = ((lc ^ lr) << 4);
    f32x4 acc[4][2];
    #pragma unroll
    for (int mt = 0; mt < 4; ++mt)
        #pragma unroll
        for (int nt = 0; nt < 2; ++nt) acc[mt][nt] = (f32x4){0.f, 0.f, 0.f, 0.f};

    const char* gA = (const char*)A_bf;
    const char* gB = (const char*)W1T_bf + koff_bytes;
    int lm = l & 15, kh = l >> 4, sw = (lm & 7) << 4;

    for (int kt = 0; kt < 12; ++kt) {
        __syncthreads();
        #pragma unroll
        for (int i = 0; i < 2; ++i) {
            int c = w * 2 + i; int r = c * 8 + lr;
            gload_lds16(gA + (size_t)(m0 + r) * 1536 + kt * 128 + xw,
                        (char*)sA + c * 1024);
        }
        #pragma unroll
        for (int i = 0; i < 4; ++i) {
            int c = w * 4 + i; int r = c * 8 + lr;
            gload_lds16(gB + (size_t)(n0 + r) * 3072 + kt * 128 + xw,
                        (char*)sB + c * 1024);
        }
        __syncthreads();
        #pragma unroll
        for (int kk = 0; kk < 2; ++kk) {
            int kb = (kk * 64 + kh * 16) ^ sw;
            bf16x8 a[4], bb[2];
            #pragma unroll
            for (int mt = 0; mt < 4; ++mt)
                a[mt] = *(const bf16x8*)((const char*)sA + (mt * 16 + lm) * 128 + kb);
            #pragma unroll
            for (int nt = 0; nt < 2; ++nt)
                bb[nt] = *(const bf16x8*)((const char*)sB + (w * 32 + nt * 16 + lm) * 128 + kb);
            #pragma unroll
            for (int mt = 0; mt < 4; ++mt)
                #pragma unroll
                for (int nt = 0; nt < 2; ++nt)
                    acc[mt][nt] = __builtin_amdgcn_mfma_f32_16x16x32_bf16(
                        a[mt], bb[nt], acc[mt][nt], 0, 0, 0);
        }
    }
    #pragma unroll
    for (int nt = 0; nt < 2; ++nt) {
        int n = n0 + w * 32 + nt * 16 + lm;
        float bv = bias ? bias[n] : 0.f;
        #pragma unroll
        for (int mt = 0; mt < 4; ++mt)
            #pragma unroll
            for (int j = 0; j < 4; ++j) {
                int row = m0 + mt * 16 + kh * 4 + j;
                C_bf[(size_t)row * 768 + n] = f2bf(acc[mt][nt][j] + bv);
            }
    }
}

// ---------------------------------------------------------------------------
// Fused layer-2+3 MFMA: block = (b,s). M=64 (d), N=384, K=768, BK=64.
// h1 = gelu(Xdoc+Xseg) computed on the fly -> bf16 -> swizzled LDS.
// W2T chunk staged via global_load_lds w/ pre-swizzled source.
// Epilogue: gelu(h2+b2)@W3 + b3 -> sigmoid -> masked max over d.
// ---------------------------------------------------------------------------
__global__ __launch_bounds__(256) void k_fused_mfma(
    const unsigned short* __restrict__ XdocB, const unsigned short* __restrict__ XsegB,
    const unsigned short* __restrict__ W2T_bf,
    const float* __restrict__ b2, const float* __restrict__ W3, const float* __restrict__ b3,
    const int* __restrict__ nd, const int* __restrict__ ns,
    float* __restrict__ out_pred, float* __restrict__ predv)
{
    __shared__ unsigned short sB[384 * 64];   // 48KB
    __shared__ unsigned short sA[64 * 64];    // 8KB
    __shared__ float sXseg[768];              // 3KB
    __shared__ float sRed[64][4];             // 1KB

    int bs = blockIdx.x;
    int b = bs >> 4;
    int t = threadIdx.x, w = t >> 6, l = t & 63;
    int lr = l >> 3, lc = l & 7;
    int xw = ((lc ^ lr) << 4);
    int lm = l & 15, kh = l >> 4, sw2 = (lm & 7) << 4;

    for (int i = t; i < 768; i += 256) sXseg[i] = bf2f(XsegB[(size_t)bs * 768 + i]);

    const int ndb = nd[b];
    const float segscale = (ns[b] > 10) ? 1.0f : 100.0f;
    const float b3v = b3[0];

    f32x4 acc[4][6];
    #pragma unroll
    for (int mt = 0; mt < 4; ++mt)
        #pragma unroll
        for (int nt = 0; nt < 6; ++nt) acc[mt][nt] = (f32x4){0.f, 0.f, 0.f, 0.f};

    int ar = t >> 2, aseg = (t & 3) * 16;           // h1 staging: row, k-base
    const char* gXd = (const char*)XdocB + (size_t)(b * 64 + ar) * 1536;
    const char* gW2 = (const char*)W2T_bf;

    for (int kt = 0; kt < 12; ++kt) {
        __syncthreads();   // prev compute done; also guards first sXseg use
        // stage W2T chunk (48KB): wave w issues 12 x 1KB
        #pragma unroll
        for (int i = 0; i < 12; ++i) {
            int c = w * 12 + i; int r = c * 8 + lr;
            gload_lds16(gW2 + (size_t)r * 1536 + kt * 128 + xw,
                        (char*)sB + c * 1024);
        }
        // stage h1 chunk: 16 elems/thread
        {
            union { uint4 v; unsigned short u[8]; } x0, x1, o0, o1;
            x0.v = *(const uint4*)(gXd + kt * 128 + aseg * 2);
            x1.v = *(const uint4*)(gXd + kt * 128 + aseg * 2 + 16);
            #pragma unroll
            for (int i = 0; i < 8; ++i)
                o0.u[i] = f2bf(gelu_exact(bf2f(x0.u[i]) + sXseg[kt * 64 + aseg + i]));
            #pragma unroll
            for (int i = 0; i < 8; ++i)
                o1.u[i] = f2bf(gelu_exact(bf2f(x1.u[i]) + sXseg[kt * 64 + aseg + 8 + i]));
            int kb0 = aseg * 2;
            *(uint4*)((char*)sA + ar * 128 + ((kb0     ) ^ ((ar & 7) << 4))) = o0.v;
            *(uint4*)((char*)sA + ar * 128 + ((kb0 + 16) ^ ((ar & 7) << 4))) = o1.v;
        }
        __syncthreads();   // vmcnt(0)+lgkmcnt(0) drained by compiler before barrier
        #pragma unroll
        for (int kk = 0; kk < 2; ++kk) {
            int kb = (kk * 64 + kh * 16) ^ sw2;
            bf16x8 a[4], bb[6];
            #pragma unroll
            for (int mt = 0; mt < 4; ++mt)
                a[mt] = *(const bf16x8*)((const char*)sA + (mt * 16 + lm) * 128 + kb);
            #pragma unroll
            for (int nt = 0; nt < 6; ++nt)
                bb[nt] = *(const bf16x8*)((const char*)sB + (w * 96 + nt * 16 + lm) * 128 + kb);
            #pragma unroll
            for (int mt = 0; mt < 4; ++mt)
                #pragma unroll
                for (int nt = 0; nt < 6; ++nt)
                    acc[mt][nt] = __builtin_amdgcn_mfma_f32_16x16x32_bf16(
                        a[mt], bb[nt], acc[mt][nt], 0, 0, 0);
        }
    }

    // epilogue: h3[row] = sum_n gelu(h2+b2[n])*W3[n]; sigmoid; masked max
    float b2v[6], w3v[6];
    #pragma unroll
    for (int nt = 0; nt < 6; ++nt) {
        int n = w * 96 + nt * 16 + lm;
        b2v[nt] = b2[n]; w3v[nt] = W3[n];
    }
    #pragma unroll
    for (int mt = 0; mt < 4; ++mt) {
        #pragma unroll
        for (int j = 0; j < 4; ++j) {
            float s = 0.f;
            #pragma unroll
            for (int nt = 0; nt < 6; ++nt)
                s += gelu_exact(acc[mt][nt][j] + b2v[nt]) * w3v[nt];
            s += __shfl_xor(s, 1); s += __shfl_xor(s, 2);
            s += __shfl_xor(s, 4); s += __shfl_xor(s, 8);
            if (lm == 0) sRed[mt * 16 + kh * 4 + j][w] = s;
        }
    }
    __syncthreads();
    if (w == 0) {
        float h3 = sRed[l][0] + sRed[l][1] + sRed[l][2] + sRed[l][3] + b3v;
        float sig = 1.0f / (1.0f + __expf(-h3));
        float val = (l < ndb) ? sig : 0.f;
        #pragma unroll
        for (int off = 32; off > 0; off >>= 1) val = fmaxf(val, __shfl_xor(val, off));
        if (l == 0) {
            float pv = segscale * val;
            out_pred[bs] = pv;
            predv[bs] = pv;
        }
    }
}

// ---------------------------------------------------------------------------
// Cosine prior per (b,s)  (unchanged)
// ---------------------------------------------------------------------------
__global__ __launch_bounds__(256) void k_cos(
    const float* __restrict__ doc, const float* __restrict__ seg,
    const float* __restrict__ dscale, const float* __restrict__ sscale,
    const int* __restrict__ nd, const int* __restrict__ ns,
    const float* __restrict__ predv, float* __restrict__ diffs)
{
    __shared__ float sS[768];
    __shared__ float wm[4];
    int bs = blockIdx.x;
    int b = bs >> 4, s = bs & 15;
    int t = threadIdx.x;
    int lane = t & 63, w = t >> 6;
    if (t < 192) ((float4*)sS)[t] = ((const float4*)(seg + (size_t)bs * 768))[t];
    __syncthreads();
    const int ndb = nd[b];
    const float ssc = sscale[bs];
    float wmax = 0.f;
    for (int d = w; d < 64; d += 4) {
        const float* dp = doc + (size_t)(b * 64 + d) * 768;
        float part = 0.f;
        #pragma unroll
        for (int i = 0; i < 12; ++i) part += sS[lane + 64 * i] * dp[lane + 64 * i];
        #pragma unroll
        for (int off = 32; off > 0; off >>= 1) part += __shfl_down(part, off);
        if (lane == 0) {
            float cosv = part * ssc * dscale[b * 64 + d];
            float sim = (d < ndb) ? (1.0f - cosv) * 0.5f : 0.f;
            wmax = fmaxf(wmax, sim);
        }
    }
    if (lane == 0) wm[w] = wmax;
    __syncthreads();
    if (t == 0) {
        float dc = fmaxf(fmaxf(wm[0], wm[1]), fmaxf(wm[2], wm[3]));
        float diff = fabsf(dc - predv[bs]);
        diffs[bs] = (s < ns[b]) ? diff : 0.f;
    }
}

// ---------------------------------------------------------------------------
// Correlation prior per b (unchanged)
// ---------------------------------------------------------------------------
__global__ __launch_bounds__(256) void k_corr(
    const float* __restrict__ seg, const float* __restrict__ smean,
    const float* __restrict__ cscale, const int* __restrict__ ns,
    const float* __restrict__ predv, float* __restrict__ corrb)
{
    __shared__ float sZ[16][772];
    __shared__ float wsum[4];
    int b = blockIdx.x;
    int t = threadIdx.x;
    for (int i = t; i < 16 * 768; i += 256) {
        int s = i / 768; int e = i - s * 768;
        sZ[s][e] = (seg[((size_t)b * 16 + s) * 768 + e] - smean[b * 16 + s]) * cscale[b * 16 + s];
    }
    __syncthreads();
    int s = t >> 4, tt = t & 15;
    const float4* z1 = (const float4*)&sZ[s][0];
    const float4* z2 = (const float4*)&sZ[tt][0];
    float dot = 0.f;
    #pragma unroll 4
    for (int e = 0; e < 192; ++e) {
        float4 a = z1[e], c = z2[e];
        dot += a.x * c.x + a.y * c.y + a.z * c.z + a.w * c.w;
    }
    float R = 0.5f * (1.0f + dot);
    int nsb = ns[b];
    float ps = predv[b * 16 + s], pt = predv[b * 16 + tt];
    float t1 = (1.f - ps) * (1.f - pt), t2 = ps * pt;
    float term = (s < nsb && tt < nsb) ? fabsf(t1 - R) * fabsf(t2 - R) : 0.f;
    #pragma unroll
    for (int off = 32; off > 0; off >>= 1) term += __shfl_down(term, off);
    int lane = t & 63, w = t >> 6;
    if (lane == 0) wsum[w] = term;
    __syncthreads();
    if (t == 0) corrb[b] = (wsum[0] + wsum[1] + wsum[2] + wsum[3]) / (float)nsb;
}

// ---------------------------------------------------------------------------
// Finalize (unchanged layout)
// ---------------------------------------------------------------------------
__global__ __launch_bounds__(256) void k_final(
    const float* __restrict__ tagg, const float* __restrict__ tis,
    const int* __restrict__ ns, const float* __restrict__ diffs,
    const float* __restrict__ corrb, float* __restrict__ out)
{
    int t = threadIdx.x;
    if (t < 32) out[t] = tagg[t];
    out[32 + t] = tis[t];
    out[32 + 256 + t] = tis[256 + t];
    if (t < 32) out[1056 + t] = (float)ns[t];
    float l1 = 0.f, l2 = 0.f;
    if (t < 32) {
        float sb = 0.f;
        #pragma unroll
        for (int s2 = 0; s2 < 16; ++s2) sb += diffs[t * 16 + s2];
        l1 = sb / (float)ns[t];
        l2 = corrb[t];
    }
    #pragma unroll
    for (int off = 16; off > 0; off >>= 1) {
        l1 += __shfl_down(l1, off);
        l2 += __shfl_down(l2, off);
    }
    if (t == 0) { out[1088] = l1 * (1.0f / 32.0f); out[1089] = l2 * (1.0f / 32.0f); }
}

// ---------------------------------------------------------------------------
extern "C" void kernel_launch(void* const* d_in, const int* in_sizes, int n_in,
                              void* d_out, int out_size, void* d_ws, size_t ws_size,
                              hipStream_t stream)
{
    const float* doc  = (const float*)d_in[0];
    const float* seg  = (const float*)d_in[1];
    const int*   nd   = (const int*)d_in[2];
    const int*   ns   = (const int*)d_in[3];
    const float* tagg = (const float*)d_in[4];
    const float* tis  = (const float*)d_in[5];
    const float* W1   = (const float*)d_in[6];   // [1536][768]
    const float* b1   = (const float*)d_in[7];
    const float* W2   = (const float*)d_in[8];   // [768][384]
    const float* b2   = (const float*)d_in[9];
    const float* W3   = (const float*)d_in[10];
    const float* b3   = (const float*)d_in[11];
    float* out = (float*)d_out;

    float* fws    = (float*)d_ws;
    float* dscale = fws;                 // 2048
    float* sscale = dscale + 2048;       // 512
    float* smean  = sscale + 512;        // 512
    float* cscale = smean + 512;         // 512
    float* predv  = cscale + 512;        // 512
    float* diffs  = predv + 512;         // 512
    float* corrb  = diffs + 512;         // 32
    unsigned short* docB  = (unsigned short*)(corrb + 32);
    unsigned short* segB  = docB + (size_t)2048 * 768;
    unsigned short* W1T   = segB + (size_t)512 * 768;     // [768][1536]
    unsigned short* W2T   = W1T + (size_t)768 * 1536;     // [384][768]
    unsigned short* XdocB = W2T + (size_t)384 * 768;      // [2048][768]
    unsigned short* XsegB = XdocB + (size_t)2048 * 768;   // [512][768]

    k_norms<<<2560, 64, 0, stream>>>(doc, seg, dscale, sscale, smean, cscale);
    k_cvt_bf16<<<1536, 256, 0, stream>>>(doc, docB, 2048 * 768 / 4);
    k_cvt_bf16<<<384, 256, 0, stream>>>(seg, segB, 512 * 768 / 4);
    k_transpose_cvt<<<dim3(12, 24), 256, 0, stream>>>(W1, W1T, 1536, 768);
    k_transpose_cvt<<<dim3(6, 12), 256, 0, stream>>>(W2, W2T, 768, 384);
    k_l1<<<dim3(32, 6), 256, 0, stream>>>(docB, W1T, nullptr, XdocB, 0);
    k_l1<<<dim3(8, 6), 256, 0, stream>>>(segB, W1T, b1, XsegB, 768 * 2);
    k_fused_mfma<<<512, 256, 0, stream>>>(XdocB, XsegB, W2T, b2, W3, b3, nd, ns,
                                          out + 544, predv);
    k_cos<<<512, 256, 0, stream>>>(doc, seg, dscale, sscale, nd, ns, predv, diffs);
    k_corr<<<32, 256, 0, stream>>>(seg, smean, cscale, ns, predv, corrb);
    k_final<<<1, 256, 0, stream>>>(tagg, tis, ns, diffs, corrb, out);
}

// Round 3
// 141.659 us; speedup vs baseline: 3.6613x; 1.2272x over previous
//
#include <hip/hip_runtime.h>
#include <hip/hip_bf16.h>
#include <math.h>

// Problem constants: B=32, S=16, D=64, E=768
#define EPSF 1e-12f

typedef short bf16x8 __attribute__((ext_vector_type(8)));
typedef float f32x4  __attribute__((ext_vector_type(4)));

__device__ __forceinline__ float gelu_exact(float x) {
    return 0.5f * x * (1.0f + erff(x * 0.70710678118f));
}
__device__ __forceinline__ float bf2f(unsigned short u) {
    return __uint_as_float(((unsigned int)u) << 16);
}
__device__ __forceinline__ unsigned short f2bf(float f) {
    unsigned int u = __float_as_uint(f);
    u += 0x7FFFu + ((u >> 16) & 1u);     // RNE
    return (unsigned short)(u >> 16);
}
__device__ __forceinline__ void gload_lds16(const void* g, void* l) {
    __builtin_amdgcn_global_load_lds(
        (const __attribute__((address_space(1))) void*)g,
        (__attribute__((address_space(3))) void*)l, 16, 0, 0);
}

// ---------------------------------------------------------------------------
// Norms + bf16 convert fused: per doc row l2 scale (+docB); per seg row l2
// scale, mean, cnorm (+segB).
// ---------------------------------------------------------------------------
__global__ __launch_bounds__(64) void k_norms(
    const float* __restrict__ doc, const float* __restrict__ seg,
    float* __restrict__ dscale, float* __restrict__ sscale,
    float* __restrict__ smean, float* __restrict__ cscale,
    unsigned short* __restrict__ docB, unsigned short* __restrict__ segB)
{
    int row = blockIdx.x;
    int lane = threadIdx.x;
    const float* src = (row < 2048) ? (doc + (size_t)row * 768)
                                    : (seg + (size_t)(row - 2048) * 768);
    unsigned short* dst = (row < 2048) ? (docB + (size_t)row * 768)
                                       : (segB + (size_t)(row - 2048) * 768);
    float ss = 0.f, sm = 0.f;
    float xv[12];
    #pragma unroll
    for (int i = 0; i < 12; ++i) {
        float x = src[lane + 64 * i];
        xv[i] = x;
        ss += x * x; sm += x;
    }
    #pragma unroll
    for (int i = 0; i < 12; ++i) dst[lane + 64 * i] = f2bf(xv[i]);
    #pragma unroll
    for (int off = 32; off > 0; off >>= 1) {
        ss += __shfl_down(ss, off);
        sm += __shfl_down(sm, off);
    }
    if (lane == 0) {
        if (row < 2048) {
            dscale[row] = rsqrtf(fmaxf(ss, EPSF));
        } else {
            int r = row - 2048;
            sscale[r] = rsqrtf(fmaxf(ss, EPSF));
            float mean = sm * (1.0f / 768.0f);
            smean[r] = mean;
            cscale[r] = rsqrtf(fmaxf(ss - sm * mean, EPSF));
        }
    }
}

// ---------------------------------------------------------------------------
// Transpose + convert: in fp32 [R][C] -> out bf16 [C][R]. 64x64 tiles.
// ---------------------------------------------------------------------------
__global__ __launch_bounds__(256) void k_transpose_cvt(
    const float* __restrict__ in, unsigned short* __restrict__ out, int R, int C)
{
    __shared__ float sT[64][65];
    int c0 = blockIdx.x * 64, r0 = blockIdx.y * 64;
    int t = threadIdx.x;
    int tr = t >> 2, tc4 = (t & 3) * 16;
    #pragma unroll
    for (int i = 0; i < 4; ++i) {
        float4 v = *(const float4*)(in + (size_t)(r0 + tr) * C + c0 + tc4 + i * 4);
        sT[tr][tc4 + i * 4 + 0] = v.x; sT[tr][tc4 + i * 4 + 1] = v.y;
        sT[tr][tc4 + i * 4 + 2] = v.z; sT[tr][tc4 + i * 4 + 3] = v.w;
    }
    __syncthreads();
    union { uint4 v; unsigned short u[8]; } o0, o1;
    #pragma unroll
    for (int i = 0; i < 8; ++i) o0.u[i] = f2bf(sT[tc4 + i][tr]);
    #pragma unroll
    for (int i = 0; i < 8; ++i) o1.u[i] = f2bf(sT[tc4 + 8 + i][tr]);
    *(uint4*)(out + (size_t)(c0 + tr) * R + r0 + tc4) = o0.v;
    *(uint4*)(out + (size_t)(c0 + tr) * R + r0 + tc4 + 8) = o1.v;
}

// ---------------------------------------------------------------------------
// Layer-1 MFMA GEMM: C_bf16[M][768] = A_bf16[M][768] @ W1T_bf16[:, koff..]^T
// BM=64, BN=128, BK=64. 4 waves; wave w -> n-tiles {2w, 2w+1} of the 8.
// (unchanged, verified)
// ---------------------------------------------------------------------------
__global__ __launch_bounds__(256) void k_l1(
    const unsigned short* __restrict__ A_bf, const unsigned short* __restrict__ W1T_bf,
    const float* __restrict__ bias, unsigned short* __restrict__ C_bf, int koff_bytes)
{
    __shared__ unsigned short sA[64 * 64];    // 8KB  (rows 128B, swizzled)
    __shared__ unsigned short sB[128 * 64];   // 16KB
    int m0 = blockIdx.x * 64, n0 = blockIdx.y * 128;
    int t = threadIdx.x, w = t >> 6, l = t & 63;
    int lr = l >> 3, lc = l & 7;
    int xw = ((lc ^ lr) << 4);
    f32x4 acc[4][2];
    #pragma unroll
    for (int mt = 0; mt < 4; ++mt)
        #pragma unroll
        for (int nt = 0; nt < 2; ++nt) acc[mt][nt] = (f32x4){0.f, 0.f, 0.f, 0.f};

    const char* gA = (const char*)A_bf;
    const char* gB = (const char*)W1T_bf + koff_bytes;
    int lm = l & 15, kh = l >> 4, sw = (lm & 7) << 4;

    for (int kt = 0; kt < 12; ++kt) {
        __syncthreads();
        #pragma unroll
        for (int i = 0; i < 2; ++i) {
            int c = w * 2 + i; int r = c * 8 + lr;
            gload_lds16(gA + (size_t)(m0 + r) * 1536 + kt * 128 + xw,
                        (char*)sA + c * 1024);
        }
        #pragma unroll
        for (int i = 0; i < 4; ++i) {
            int c = w * 4 + i; int r = c * 8 + lr;
            gload_lds16(gB + (size_t)(n0 + r) * 3072 + kt * 128 + xw,
                        (char*)sB + c * 1024);
        }
        __syncthreads();
        #pragma unroll
        for (int kk = 0; kk < 2; ++kk) {
            int kb = (kk * 64 + kh * 16) ^ sw;
            bf16x8 a[4], bb[2];
            #pragma unroll
            for (int mt = 0; mt < 4; ++mt)
                a[mt] = *(const bf16x8*)((const char*)sA + (mt * 16 + lm) * 128 + kb);
            #pragma unroll
            for (int nt = 0; nt < 2; ++nt)
                bb[nt] = *(const bf16x8*)((const char*)sB + (w * 32 + nt * 16 + lm) * 128 + kb);
            #pragma unroll
            for (int mt = 0; mt < 4; ++mt)
                #pragma unroll
                for (int nt = 0; nt < 2; ++nt)
                    acc[mt][nt] = __builtin_amdgcn_mfma_f32_16x16x32_bf16(
                        a[mt], bb[nt], acc[mt][nt], 0, 0, 0);
        }
    }
    #pragma unroll
    for (int nt = 0; nt < 2; ++nt) {
        int n = n0 + w * 32 + nt * 16 + lm;
        float bv = bias ? bias[n] : 0.f;
        #pragma unroll
        for (int mt = 0; mt < 4; ++mt)
            #pragma unroll
            for (int j = 0; j < 4; ++j) {
                int row = m0 + mt * 16 + kh * 4 + j;
                C_bf[(size_t)row * 768 + n] = f2bf(acc[mt][nt][j] + bv);
            }
    }
}

// ---------------------------------------------------------------------------
// Fused layer-2+3 MFMA: block = (b,s). M=64 (d), N=384, K=768, BK=64.
// h1 = gelu(Xdoc+Xseg) on the fly -> bf16 -> swizzled LDS (double-buffered,
// ONE barrier per K-step). W2T B-fragments read DIRECTLY from global/L2 into
// registers (no LDS staging, no vmcnt-drain serialization).
// Epilogue: gelu(h2+b2)@W3 + b3 -> sigmoid -> masked max over d.
// ---------------------------------------------------------------------------
__global__ __launch_bounds__(256) void k_fused_mfma(
    const unsigned short* __restrict__ XdocB, const unsigned short* __restrict__ XsegB,
    const unsigned short* __restrict__ W2T_bf,
    const float* __restrict__ b2, const float* __restrict__ W3, const float* __restrict__ b3,
    const int* __restrict__ nd, const int* __restrict__ ns,
    float* __restrict__ out_pred, float* __restrict__ predv)
{
    __shared__ unsigned short sA0[64 * 64];   // 8KB, swizzled rows of 128B
    __shared__ unsigned short sA1[64 * 64];   // 8KB
    __shared__ float sXseg[768];              // 3KB
    __shared__ float sRed[64][4];             // 1KB

    int bs = blockIdx.x;
    int b = bs >> 4;
    int t = threadIdx.x, w = t >> 6, l = t & 63;
    int lm = l & 15, kh = l >> 4, sw2 = (lm & 7) << 4;

    for (int i = t; i < 768; i += 256) sXseg[i] = bf2f(XsegB[(size_t)bs * 768 + i]);

    const int ndb = nd[b];
    const float segscale = (ns[b] > 10) ? 1.0f : 100.0f;
    const float b3v = b3[0];

    f32x4 acc[4][6];
    #pragma unroll
    for (int mt = 0; mt < 4; ++mt)
        #pragma unroll
        for (int nt = 0; nt < 6; ++nt) acc[mt][nt] = (f32x4){0.f, 0.f, 0.f, 0.f};

    int ar = t >> 2, ak = (t & 3) * 16;        // h1 staging: row 0..63, k-base
    int asw = (ar & 7) << 4;
    const char* gXd = (const char*)XdocB + (size_t)(b * 64 + ar) * 1536;
    // B fragments: row n = w*96 + nt*16 + lm ; k = kt*64 + kk*32 + kh*8
    const unsigned short* gW2w = W2T_bf + (size_t)(w * 96 + lm) * 768 + kh * 8;

    #define STAGE_H1(KT, DST)                                                   \
    {                                                                           \
        union { uint4 v; unsigned short u[8]; } x0_, x1_, o0_, o1_;             \
        x0_.v = *(const uint4*)(gXd + (KT) * 128 + (ak * 2));                   \
        x1_.v = *(const uint4*)(gXd + (KT) * 128 + (ak * 2) + 16);              \
        _Pragma("unroll")                                                       \
        for (int i_ = 0; i_ < 8; ++i_)                                          \
            o0_.u[i_] = f2bf(gelu_exact(bf2f(x0_.u[i_]) + sXseg[(KT) * 64 + ak + i_])); \
        _Pragma("unroll")                                                       \
        for (int i_ = 0; i_ < 8; ++i_)                                          \
            o1_.u[i_] = f2bf(gelu_exact(bf2f(x1_.u[i_]) + sXseg[(KT) * 64 + ak + 8 + i_])); \
        *(uint4*)((char*)(DST) + ar * 128 + ((ak * 2) ^ asw)) = o0_.v;          \
        *(uint4*)((char*)(DST) + ar * 128 + (((ak * 2) + 16) ^ asw)) = o1_.v;   \
    }

    __syncthreads();          // sXseg ready
    STAGE_H1(0, sA0);

    #pragma unroll
    for (int kt = 0; kt < 12; ++kt) {
        unsigned short* cbuf = (kt & 1) ? sA1 : sA0;
        unsigned short* nbuf = (kt & 1) ? sA0 : sA1;
        __syncthreads();      // stage(kt) writes done; prev reads of nbuf done
        if (kt < 11) STAGE_H1(kt + 1, nbuf);
        #pragma unroll
        for (int kk = 0; kk < 2; ++kk) {
            int kb = (kk * 64 + kh * 16) ^ sw2;
            bf16x8 a[4], bb[6];
            #pragma unroll
            for (int mt = 0; mt < 4; ++mt)
                a[mt] = *(const bf16x8*)((const char*)cbuf + (mt * 16 + lm) * 128 + kb);
            #pragma unroll
            for (int nt = 0; nt < 6; ++nt)
                bb[nt] = *(const bf16x8*)(gW2w + (size_t)nt * 16 * 768 + kt * 64 + kk * 32);
            #pragma unroll
            for (int mt = 0; mt < 4; ++mt)
                #pragma unroll
                for (int nt = 0; nt < 6; ++nt)
                    acc[mt][nt] = __builtin_amdgcn_mfma_f32_16x16x32_bf16(
                        a[mt], bb[nt], acc[mt][nt], 0, 0, 0);
        }
    }
    #undef STAGE_H1

    // epilogue: h3[row] = sum_n gelu(h2+b2[n])*W3[n]; sigmoid; masked max
    float b2v[6], w3v[6];
    #pragma unroll
    for (int nt = 0; nt < 6; ++nt) {
        int n = w * 96 + nt * 16 + lm;
        b2v[nt] = b2[n]; w3v[nt] = W3[n];
    }
    #pragma unroll
    for (int mt = 0; mt < 4; ++mt) {
        #pragma unroll
        for (int j = 0; j < 4; ++j) {
            float s = 0.f;
            #pragma unroll
            for (int nt = 0; nt < 6; ++nt)
                s += gelu_exact(acc[mt][nt][j] + b2v[nt]) * w3v[nt];
            s += __shfl_xor(s, 1); s += __shfl_xor(s, 2);
            s += __shfl_xor(s, 4); s += __shfl_xor(s, 8);
            if (lm == 0) sRed[mt * 16 + kh * 4 + j][w] = s;
        }
    }
    __syncthreads();
    if (w == 0) {
        float h3 = sRed[l][0] + sRed[l][1] + sRed[l][2] + sRed[l][3] + b3v;
        float sig = 1.0f / (1.0f + __expf(-h3));
        float val = (l < ndb) ? sig : 0.f;
        #pragma unroll
        for (int off = 32; off > 0; off >>= 1) val = fmaxf(val, __shfl_xor(val, off));
        if (l == 0) {
            float pv = segscale * val;
            out_pred[bs] = pv;
            predv[bs] = pv;
        }
    }
}

// ---------------------------------------------------------------------------
// Cosine prior per (b,s)  (unchanged)
// ---------------------------------------------------------------------------
__global__ __launch_bounds__(256) void k_cos(
    const float* __restrict__ doc, const float* __restrict__ seg,
    const float* __restrict__ dscale, const float* __restrict__ sscale,
    const int* __restrict__ nd, const int* __restrict__ ns,
    const float* __restrict__ predv, float* __restrict__ diffs)
{
    __shared__ float sS[768];
    __shared__ float wm[4];
    int bs = blockIdx.x;
    int b = bs >> 4, s = bs & 15;
    int t = threadIdx.x;
    int lane = t & 63, w = t >> 6;
    if (t < 192) ((float4*)sS)[t] = ((const float4*)(seg + (size_t)bs * 768))[t];
    __syncthreads();
    const int ndb = nd[b];
    const float ssc = sscale[bs];
    float wmax = 0.f;
    for (int d = w; d < 64; d += 4) {
        const float* dp = doc + (size_t)(b * 64 + d) * 768;
        float part = 0.f;
        #pragma unroll
        for (int i = 0; i < 12; ++i) part += sS[lane + 64 * i] * dp[lane + 64 * i];
        #pragma unroll
        for (int off = 32; off > 0; off >>= 1) part += __shfl_down(part, off);
        if (lane == 0) {
            float cosv = part * ssc * dscale[b * 64 + d];
            float sim = (d < ndb) ? (1.0f - cosv) * 0.5f : 0.f;
            wmax = fmaxf(wmax, sim);
        }
    }
    if (lane == 0) wm[w] = wmax;
    __syncthreads();
    if (t == 0) {
        float dc = fmaxf(fmaxf(wm[0], wm[1]), fmaxf(wm[2], wm[3]));
        float diff = fabsf(dc - predv[bs]);
        diffs[bs] = (s < ns[b]) ? diff : 0.f;
    }
}

// ---------------------------------------------------------------------------
// Correlation prior per b (unchanged)
// ---------------------------------------------------------------------------
__global__ __launch_bounds__(256) void k_corr(
    const float* __restrict__ seg, const float* __restrict__ smean,
    const float* __restrict__ cscale, const int* __restrict__ ns,
    const float* __restrict__ predv, float* __restrict__ corrb)
{
    __shared__ float sZ[16][772];
    __shared__ float wsum[4];
    int b = blockIdx.x;
    int t = threadIdx.x;
    for (int i = t; i < 16 * 768; i += 256) {
        int s = i / 768; int e = i - s * 768;
        sZ[s][e] = (seg[((size_t)b * 16 + s) * 768 + e] - smean[b * 16 + s]) * cscale[b * 16 + s];
    }
    __syncthreads();
    int s = t >> 4, tt = t & 15;
    const float4* z1 = (const float4*)&sZ[s][0];
    const float4* z2 = (const float4*)&sZ[tt][0];
    float dot = 0.f;
    #pragma unroll 4
    for (int e = 0; e < 192; ++e) {
        float4 a = z1[e], c = z2[e];
        dot += a.x * c.x + a.y * c.y + a.z * c.z + a.w * c.w;
    }
    float R = 0.5f * (1.0f + dot);
    int nsb = ns[b];
    float ps = predv[b * 16 + s], pt = predv[b * 16 + tt];
    float t1 = (1.f - ps) * (1.f - pt), t2 = ps * pt;
    float term = (s < nsb && tt < nsb) ? fabsf(t1 - R) * fabsf(t2 - R) : 0.f;
    #pragma unroll
    for (int off = 32; off > 0; off >>= 1) term += __shfl_down(term, off);
    int lane = t & 63, w = t >> 6;
    if (lane == 0) wsum[w] = term;
    __syncthreads();
    if (t == 0) corrb[b] = (wsum[0] + wsum[1] + wsum[2] + wsum[3]) / (float)nsb;
}

// ---------------------------------------------------------------------------
// Finalize (unchanged layout)
// ---------------------------------------------------------------------------
__global__ __launch_bounds__(256) void k_final(
    const float* __restrict__ tagg, const float* __restrict__ tis,
    const int* __restrict__ ns, const float* __restrict__ diffs,
    const float* __restrict__ corrb, float* __restrict__ out)
{
    int t = threadIdx.x;
    if (t < 32) out[t] = tagg[t];
    out[32 + t] = tis[t];
    out[32 + 256 + t] = tis[256 + t];
    if (t < 32) out[1056 + t] = (float)ns[t];
    float l1 = 0.f, l2 = 0.f;
    if (t < 32) {
        float sb = 0.f;
        #pragma unroll
        for (int s2 = 0; s2 < 16; ++s2) sb += diffs[t * 16 + s2];
        l1 = sb / (float)ns[t];
        l2 = corrb[t];
    }
    #pragma unroll
    for (int off = 16; off > 0; off >>= 1) {
        l1 += __shfl_down(l1, off);
        l2 += __shfl_down(l2, off);
    }
    if (t == 0) { out[1088] = l1 * (1.0f / 32.0f); out[1089] = l2 * (1.0f / 32.0f); }
}

// ---------------------------------------------------------------------------
extern "C" void kernel_launch(void* const* d_in, const int* in_sizes, int n_in,
                              void* d_out, int out_size, void* d_ws, size_t ws_size,
                              hipStream_t stream)
{
    const float* doc  = (const float*)d_in[0];
    const float* seg  = (const float*)d_in[1];
    const int*   nd   = (const int*)d_in[2];
    const int*   ns   = (const int*)d_in[3];
    const float* tagg = (const float*)d_in[4];
    const float* tis  = (const float*)d_in[5];
    const float* W1   = (const float*)d_in[6];   // [1536][768]
    const float* b1   = (const float*)d_in[7];
    const float* W2   = (const float*)d_in[8];   // [768][384]
    const float* b2   = (const float*)d_in[9];
    const float* W3   = (const float*)d_in[10];
    const float* b3   = (const float*)d_in[11];
    float* out = (float*)d_out;

    float* fws    = (float*)d_ws;
    float* dscale = fws;                 // 2048
    float* sscale = dscale + 2048;       // 512
    float* smean  = sscale + 512;        // 512
    float* cscale = smean + 512;         // 512
    float* predv  = cscale + 512;        // 512
    float* diffs  = predv + 512;         // 512
    float* corrb  = diffs + 512;         // 32
    unsigned short* docB  = (unsigned short*)(corrb + 32);
    unsigned short* segB  = docB + (size_t)2048 * 768;
    unsigned short* W1T   = segB + (size_t)512 * 768;     // [768][1536]
    unsigned short* W2T   = W1T + (size_t)768 * 1536;     // [384][768]
    unsigned short* XdocB = W2T + (size_t)384 * 768;      // [2048][768]
    unsigned short* XsegB = XdocB + (size_t)2048 * 768;   // [512][768]

    k_norms<<<2560, 64, 0, stream>>>(doc, seg, dscale, sscale, smean, cscale, docB, segB);
    k_transpose_cvt<<<dim3(12, 24), 256, 0, stream>>>(W1, W1T, 1536, 768);
    k_transpose_cvt<<<dim3(6, 12), 256, 0, stream>>>(W2, W2T, 768, 384);
    k_l1<<<dim3(32, 6), 256, 0, stream>>>(docB, W1T, nullptr, XdocB, 0);
    k_l1<<<dim3(8, 6), 256, 0, stream>>>(segB, W1T, b1, XsegB, 768 * 2);
    k_fused_mfma<<<512, 256, 0, stream>>>(XdocB, XsegB, W2T, b2, W3, b3, nd, ns,
                                          out + 544, predv);
    k_cos<<<512, 256, 0, stream>>>(doc, seg, dscale, sscale, nd, ns, predv, diffs);
    k_corr<<<32, 256, 0, stream>>>(seg, smean, cscale, ns, predv, corrb);
    k_final<<<1, 256, 0, stream>>>(tagg, tis, ns, diffs, corrb, out);
}

// Round 4
// 109.517 us; speedup vs baseline: 4.7359x; 1.2935x over previous
//
#include <hip/hip_runtime.h>
#include <hip/hip_bf16.h>
#include <math.h>

// Problem constants: B=32, S=16, D=64, E=768
#define EPSF 1e-12f

typedef short bf16x8 __attribute__((ext_vector_type(8)));
typedef float f32x4  __attribute__((ext_vector_type(4)));

// tanh-approx GELU via native exp2/rcp: max abs err ~3e-4 vs exact erf-gelu.
// gelu(x) ~= x * sigmoid(1.59577(x + 0.044715 x^3))
//          = x * rcp(1 + exp2(-2.302118 * x * (1 + 0.044715 x^2)))
__device__ __forceinline__ float gelu_fast(float x) {
    float x2 = x * x;
    float z = -2.3021184f * x * fmaf(0.044715f, x2, 1.0f);
    float u = __builtin_amdgcn_exp2f(z);
    return x * __builtin_amdgcn_rcpf(1.0f + u);
}
__device__ __forceinline__ float sigmoid_fast(float x) {
    float u = __builtin_amdgcn_exp2f(-1.44269504f * x);
    return __builtin_amdgcn_rcpf(1.0f + u);
}
__device__ __forceinline__ float bf2f(unsigned short u) {
    return __uint_as_float(((unsigned int)u) << 16);
}
__device__ __forceinline__ unsigned short f2bf(float f) {
    unsigned int u = __float_as_uint(f);
    u += 0x7FFFu + ((u >> 16) & 1u);     // RNE
    return (unsigned short)(u >> 16);
}

// ---------------------------------------------------------------------------
// Norms + bf16 convert fused.
// ---------------------------------------------------------------------------
__global__ __launch_bounds__(64) void k_norms(
    const float* __restrict__ doc, const float* __restrict__ seg,
    float* __restrict__ dscale, float* __restrict__ sscale,
    float* __restrict__ smean, float* __restrict__ cscale,
    unsigned short* __restrict__ docB, unsigned short* __restrict__ segB)
{
    int row = blockIdx.x;
    int lane = threadIdx.x;
    const float* src = (row < 2048) ? (doc + (size_t)row * 768)
                                    : (seg + (size_t)(row - 2048) * 768);
    unsigned short* dst = (row < 2048) ? (docB + (size_t)row * 768)
                                       : (segB + (size_t)(row - 2048) * 768);
    float ss = 0.f, sm = 0.f;
    float xv[12];
    #pragma unroll
    for (int i = 0; i < 12; ++i) {
        float x = src[lane + 64 * i];
        xv[i] = x;
        ss += x * x; sm += x;
    }
    #pragma unroll
    for (int i = 0; i < 12; ++i) dst[lane + 64 * i] = f2bf(xv[i]);
    #pragma unroll
    for (int off = 32; off > 0; off >>= 1) {
        ss += __shfl_down(ss, off);
        sm += __shfl_down(sm, off);
    }
    if (lane == 0) {
        if (row < 2048) {
            dscale[row] = rsqrtf(fmaxf(ss, EPSF));
        } else {
            int r = row - 2048;
            sscale[r] = rsqrtf(fmaxf(ss, EPSF));
            float mean = sm * (1.0f / 768.0f);
            smean[r] = mean;
            cscale[r] = rsqrtf(fmaxf(ss - sm * mean, EPSF));
        }
    }
}

// ---------------------------------------------------------------------------
// Transpose + convert: in fp32 [R][C] -> out bf16 [C][R]. 64x64 tiles.
// ---------------------------------------------------------------------------
__global__ __launch_bounds__(256) void k_transpose_cvt(
    const float* __restrict__ in, unsigned short* __restrict__ out, int R, int C)
{
    __shared__ float sT[64][65];
    int c0 = blockIdx.x * 64, r0 = blockIdx.y * 64;
    int t = threadIdx.x;
    int tr = t >> 2, tc4 = (t & 3) * 16;
    #pragma unroll
    for (int i = 0; i < 4; ++i) {
        float4 v = *(const float4*)(in + (size_t)(r0 + tr) * C + c0 + tc4 + i * 4);
        sT[tr][tc4 + i * 4 + 0] = v.x; sT[tr][tc4 + i * 4 + 1] = v.y;
        sT[tr][tc4 + i * 4 + 2] = v.z; sT[tr][tc4 + i * 4 + 3] = v.w;
    }
    __syncthreads();
    union { uint4 v; unsigned short u[8]; } o0, o1;
    #pragma unroll
    for (int i = 0; i < 8; ++i) o0.u[i] = f2bf(sT[tc4 + i][tr]);
    #pragma unroll
    for (int i = 0; i < 8; ++i) o1.u[i] = f2bf(sT[tc4 + 8 + i][tr]);
    *(uint4*)(out + (size_t)(c0 + tr) * R + r0 + tc4) = o0.v;
    *(uint4*)(out + (size_t)(c0 + tr) * R + r0 + tc4 + 8) = o1.v;
}

// ---------------------------------------------------------------------------
// Layer-1 MFMA GEMM, no-LDS direct-register fragments (A and W1T are L2-hot).
// Grid (40, 6): mb<32 -> doc rows (W1 top half, no bias); mb>=32 -> seg rows
// (W1 bottom half, +b1). BM=64, BN=128; wave w owns n-tiles {2w,2w+1}.
// ---------------------------------------------------------------------------
__global__ __launch_bounds__(256) void k_l1(
    const unsigned short* __restrict__ docB, const unsigned short* __restrict__ segB,
    const unsigned short* __restrict__ W1T_bf, const float* __restrict__ b1,
    unsigned short* __restrict__ XdocB, unsigned short* __restrict__ XsegB)
{
    int mb = blockIdx.x;
    int n0 = blockIdx.y * 128;
    int t = threadIdx.x, w = t >> 6, l = t & 63;
    int lm = l & 15, kh = l >> 4;
    bool isdoc = (mb < 32);
    int m0 = isdoc ? mb * 64 : (mb - 32) * 64;
    const unsigned short* A = isdoc ? docB : segB;
    int koff = isdoc ? 0 : 768;
    unsigned short* C = isdoc ? XdocB : XsegB;

    const unsigned short* gA = A + (size_t)(m0 + lm) * 768 + kh * 8;
    const unsigned short* gB = W1T_bf + (size_t)(n0 + w * 32 + lm) * 1536 + koff + kh * 8;

    f32x4 acc[4][2];
    #pragma unroll
    for (int mt = 0; mt < 4; ++mt)
        #pragma unroll
        for (int nt = 0; nt < 2; ++nt) acc[mt][nt] = (f32x4){0.f, 0.f, 0.f, 0.f};

    for (int kt = 0; kt < 12; ++kt) {
        #pragma unroll
        for (int kk = 0; kk < 2; ++kk) {
            int ko = kt * 64 + kk * 32;
            bf16x8 a[4], bb[2];
            #pragma unroll
            for (int mt = 0; mt < 4; ++mt)
                a[mt] = *(const bf16x8*)(gA + (size_t)mt * 16 * 768 + ko);
            #pragma unroll
            for (int nt = 0; nt < 2; ++nt)
                bb[nt] = *(const bf16x8*)(gB + (size_t)nt * 16 * 1536 + ko);
            #pragma unroll
            for (int mt = 0; mt < 4; ++mt)
                #pragma unroll
                for (int nt = 0; nt < 2; ++nt)
                    acc[mt][nt] = __builtin_amdgcn_mfma_f32_16x16x32_bf16(
                        a[mt], bb[nt], acc[mt][nt], 0, 0, 0);
        }
    }
    #pragma unroll
    for (int nt = 0; nt < 2; ++nt) {
        int n = n0 + w * 32 + nt * 16 + lm;
        float bv = isdoc ? 0.f : b1[n];
        #pragma unroll
        for (int mt = 0; mt < 4; ++mt)
            #pragma unroll
            for (int j = 0; j < 4; ++j) {
                int row = m0 + mt * 16 + kh * 4 + j;
                C[(size_t)row * 768 + n] = f2bf(acc[mt][nt][j] + bv);
            }
    }
}

// ---------------------------------------------------------------------------
// Fused layer-2+3 MFMA: block = (b,s). M=64 (d), N=384, K=768, BK=64.
// h1 = gelu_fast(Xdoc+Xseg) on the fly -> bf16 -> swizzled LDS (double-buf,
// one barrier per K-step). W2T B-fragments read directly from L2 to regs.
// ---------------------------------------------------------------------------
__global__ __launch_bounds__(256) void k_fused_mfma(
    const unsigned short* __restrict__ XdocB, const unsigned short* __restrict__ XsegB,
    const unsigned short* __restrict__ W2T_bf,
    const float* __restrict__ b2, const float* __restrict__ W3, const float* __restrict__ b3,
    const int* __restrict__ nd, const int* __restrict__ ns,
    float* __restrict__ out_pred, float* __restrict__ predv)
{
    __shared__ unsigned short sA0[64 * 64];   // 8KB, swizzled rows of 128B
    __shared__ unsigned short sA1[64 * 64];   // 8KB
    __shared__ float sXseg[768];              // 3KB
    __shared__ float sRed[64][4];             // 1KB

    int bs = blockIdx.x;
    int b = bs >> 4;
    int t = threadIdx.x, w = t >> 6, l = t & 63;
    int lm = l & 15, kh = l >> 4, sw2 = (lm & 7) << 4;

    for (int i = t; i < 768; i += 256) sXseg[i] = bf2f(XsegB[(size_t)bs * 768 + i]);

    const int ndb = nd[b];
    const float segscale = (ns[b] > 10) ? 1.0f : 100.0f;
    const float b3v = b3[0];

    f32x4 acc[4][6];
    #pragma unroll
    for (int mt = 0; mt < 4; ++mt)
        #pragma unroll
        for (int nt = 0; nt < 6; ++nt) acc[mt][nt] = (f32x4){0.f, 0.f, 0.f, 0.f};

    int ar = t >> 2, ak = (t & 3) * 16;        // h1 staging: row 0..63, k-base
    int asw = (ar & 7) << 4;
    const char* gXd = (const char*)XdocB + (size_t)(b * 64 + ar) * 1536;
    const unsigned short* gW2w = W2T_bf + (size_t)(w * 96 + lm) * 768 + kh * 8;

    #define STAGE_H1(KT, DST)                                                   \
    {                                                                           \
        union { uint4 v; unsigned short u[8]; } x0_, x1_, o0_, o1_;             \
        x0_.v = *(const uint4*)(gXd + (KT) * 128 + (ak * 2));                   \
        x1_.v = *(const uint4*)(gXd + (KT) * 128 + (ak * 2) + 16);              \
        _Pragma("unroll")                                                       \
        for (int i_ = 0; i_ < 8; ++i_)                                          \
            o0_.u[i_] = f2bf(gelu_fast(bf2f(x0_.u[i_]) + sXseg[(KT) * 64 + ak + i_])); \
        _Pragma("unroll")                                                       \
        for (int i_ = 0; i_ < 8; ++i_)                                          \
            o1_.u[i_] = f2bf(gelu_fast(bf2f(x1_.u[i_]) + sXseg[(KT) * 64 + ak + 8 + i_])); \
        *(uint4*)((char*)(DST) + ar * 128 + ((ak * 2) ^ asw)) = o0_.v;          \
        *(uint4*)((char*)(DST) + ar * 128 + (((ak * 2) + 16) ^ asw)) = o1_.v;   \
    }

    __syncthreads();          // sXseg ready
    STAGE_H1(0, sA0);

    #pragma unroll
    for (int kt = 0; kt < 12; ++kt) {
        unsigned short* cbuf = (kt & 1) ? sA1 : sA0;
        unsigned short* nbuf = (kt & 1) ? sA0 : sA1;
        __syncthreads();      // stage(kt) writes done; prev reads of nbuf done
        if (kt < 11) STAGE_H1(kt + 1, nbuf);
        #pragma unroll
        for (int kk = 0; kk < 2; ++kk) {
            int kb = (kk * 64 + kh * 16) ^ sw2;
            bf16x8 a[4], bb[6];
            #pragma unroll
            for (int mt = 0; mt < 4; ++mt)
                a[mt] = *(const bf16x8*)((const char*)cbuf + (mt * 16 + lm) * 128 + kb);
            #pragma unroll
            for (int nt = 0; nt < 6; ++nt)
                bb[nt] = *(const bf16x8*)(gW2w + (size_t)nt * 16 * 768 + kt * 64 + kk * 32);
            #pragma unroll
            for (int mt = 0; mt < 4; ++mt)
                #pragma unroll
                for (int nt = 0; nt < 6; ++nt)
                    acc[mt][nt] = __builtin_amdgcn_mfma_f32_16x16x32_bf16(
                        a[mt], bb[nt], acc[mt][nt], 0, 0, 0);
        }
    }
    #undef STAGE_H1

    // epilogue: h3[row] = sum_n gelu(h2+b2[n])*W3[n]; sigmoid; masked max
    float b2v[6], w3v[6];
    #pragma unroll
    for (int nt = 0; nt < 6; ++nt) {
        int n = w * 96 + nt * 16 + lm;
        b2v[nt] = b2[n]; w3v[nt] = W3[n];
    }
    #pragma unroll
    for (int mt = 0; mt < 4; ++mt) {
        #pragma unroll
        for (int j = 0; j < 4; ++j) {
            float s = 0.f;
            #pragma unroll
            for (int nt = 0; nt < 6; ++nt)
                s += gelu_fast(acc[mt][nt][j] + b2v[nt]) * w3v[nt];
            s += __shfl_xor(s, 1); s += __shfl_xor(s, 2);
            s += __shfl_xor(s, 4); s += __shfl_xor(s, 8);
            if (lm == 0) sRed[mt * 16 + kh * 4 + j][w] = s;
        }
    }
    __syncthreads();
    if (w == 0) {
        float h3 = sRed[l][0] + sRed[l][1] + sRed[l][2] + sRed[l][3] + b3v;
        float sig = sigmoid_fast(h3);
        float val = (l < ndb) ? sig : 0.f;
        #pragma unroll
        for (int off = 32; off > 0; off >>= 1) val = fmaxf(val, __shfl_xor(val, off));
        if (l == 0) {
            float pv = segscale * val;
            out_pred[bs] = pv;
            predv[bs] = pv;
        }
    }
}

// ---------------------------------------------------------------------------
// Cosine prior via MFMA: one block per b. cos[s,d] = (segB@docB^T)*scales.
// Wave w owns d-tile [w*16, w*16+16). Direct-register fragments (L2-hot).
// ---------------------------------------------------------------------------
__global__ __launch_bounds__(256) void k_cos_mfma(
    const unsigned short* __restrict__ docB, const unsigned short* __restrict__ segB,
    const float* __restrict__ dscale, const float* __restrict__ sscale,
    const int* __restrict__ nd, const int* __restrict__ ns,
    const float* __restrict__ predv, float* __restrict__ diffs)
{
    __shared__ float sRed[16][4];
    int b = blockIdx.x;
    int t = threadIdx.x, w = t >> 6, l = t & 63;
    int lm = l & 15, kh = l >> 4;

    const unsigned short* gS = segB + (size_t)(b * 16 + lm) * 768 + kh * 8;
    const unsigned short* gD = docB + (size_t)(b * 64 + w * 16 + lm) * 768 + kh * 8;
    f32x4 acc = (f32x4){0.f, 0.f, 0.f, 0.f};
    for (int kt = 0; kt < 24; ++kt) {
        bf16x8 a = *(const bf16x8*)(gS + kt * 32);
        bf16x8 bb = *(const bf16x8*)(gD + kt * 32);
        acc = __builtin_amdgcn_mfma_f32_16x16x32_bf16(a, bb, acc, 0, 0, 0);
    }
    // lane holds dot(seg_s, doc_d) for s=kh*4+j (j=0..3), d=w*16+lm
    int ndb = nd[b];
    int d = w * 16 + lm;
    float dsc = dscale[b * 64 + d];
    #pragma unroll
    for (int j = 0; j < 4; ++j) {
        int s = kh * 4 + j;
        float cosv = acc[j] * sscale[b * 16 + s] * dsc;
        float sim = (d < ndb) ? (1.0f - cosv) * 0.5f : 0.f;
        sim = fmaxf(sim, __shfl_xor(sim, 1));
        sim = fmaxf(sim, __shfl_xor(sim, 2));
        sim = fmaxf(sim, __shfl_xor(sim, 4));
        sim = fmaxf(sim, __shfl_xor(sim, 8));
        if (lm == 0) sRed[s][w] = sim;
    }
    __syncthreads();
    if (t < 16) {
        float dc = fmaxf(fmaxf(sRed[t][0], sRed[t][1]), fmaxf(sRed[t][2], sRed[t][3]));
        float diff = fabsf(dc - predv[b * 16 + t]);
        diffs[b * 16 + t] = (t < ns[b]) ? diff : 0.f;
    }
}

// ---------------------------------------------------------------------------
// Correlation prior per b (fp32, unchanged — accuracy-safe, tiny)
// ---------------------------------------------------------------------------
__global__ __launch_bounds__(256) void k_corr(
    const float* __restrict__ seg, const float* __restrict__ smean,
    const float* __restrict__ cscale, const int* __restrict__ ns,
    const float* __restrict__ predv, float* __restrict__ corrb)
{
    __shared__ float sZ[16][772];
    __shared__ float wsum[4];
    int b = blockIdx.x;
    int t = threadIdx.x;
    for (int i = t; i < 16 * 768; i += 256) {
        int s = i / 768; int e = i - s * 768;
        sZ[s][e] = (seg[((size_t)b * 16 + s) * 768 + e] - smean[b * 16 + s]) * cscale[b * 16 + s];
    }
    __syncthreads();
    int s = t >> 4, tt = t & 15;
    const float4* z1 = (const float4*)&sZ[s][0];
    const float4* z2 = (const float4*)&sZ[tt][0];
    float dot = 0.f;
    #pragma unroll 4
    for (int e = 0; e < 192; ++e) {
        float4 a = z1[e], c = z2[e];
        dot += a.x * c.x + a.y * c.y + a.z * c.z + a.w * c.w;
    }
    float R = 0.5f * (1.0f + dot);
    int nsb = ns[b];
    float ps = predv[b * 16 + s], pt = predv[b * 16 + tt];
    float t1 = (1.f - ps) * (1.f - pt), t2 = ps * pt;
    float term = (s < nsb && tt < nsb) ? fabsf(t1 - R) * fabsf(t2 - R) : 0.f;
    #pragma unroll
    for (int off = 32; off > 0; off >>= 1) term += __shfl_down(term, off);
    int lane = t & 63, w = t >> 6;
    if (lane == 0) wsum[w] = term;
    __syncthreads();
    if (t == 0) corrb[b] = (wsum[0] + wsum[1] + wsum[2] + wsum[3]) / (float)nsb;
}

// ---------------------------------------------------------------------------
// Finalize (unchanged layout)
// ---------------------------------------------------------------------------
__global__ __launch_bounds__(256) void k_final(
    const float* __restrict__ tagg, const float* __restrict__ tis,
    const int* __restrict__ ns, const float* __restrict__ diffs,
    const float* __restrict__ corrb, float* __restrict__ out)
{
    int t = threadIdx.x;
    if (t < 32) out[t] = tagg[t];
    out[32 + t] = tis[t];
    out[32 + 256 + t] = tis[256 + t];
    if (t < 32) out[1056 + t] = (float)ns[t];
    float l1 = 0.f, l2 = 0.f;
    if (t < 32) {
        float sb = 0.f;
        #pragma unroll
        for (int s2 = 0; s2 < 16; ++s2) sb += diffs[t * 16 + s2];
        l1 = sb / (float)ns[t];
        l2 = corrb[t];
    }
    #pragma unroll
    for (int off = 16; off > 0; off >>= 1) {
        l1 += __shfl_down(l1, off);
        l2 += __shfl_down(l2, off);
    }
    if (t == 0) { out[1088] = l1 * (1.0f / 32.0f); out[1089] = l2 * (1.0f / 32.0f); }
}

// ---------------------------------------------------------------------------
extern "C" void kernel_launch(void* const* d_in, const int* in_sizes, int n_in,
                              void* d_out, int out_size, void* d_ws, size_t ws_size,
                              hipStream_t stream)
{
    const float* doc  = (const float*)d_in[0];
    const float* seg  = (const float*)d_in[1];
    const int*   nd   = (const int*)d_in[2];
    const int*   ns   = (const int*)d_in[3];
    const float* tagg = (const float*)d_in[4];
    const float* tis  = (const float*)d_in[5];
    const float* W1   = (const float*)d_in[6];   // [1536][768]
    const float* b1   = (const float*)d_in[7];
    const float* W2   = (const float*)d_in[8];   // [768][384]
    const float* b2   = (const float*)d_in[9];
    const float* W3   = (const float*)d_in[10];
    const float* b3   = (const float*)d_in[11];
    float* out = (float*)d_out;

    float* fws    = (float*)d_ws;
    float* dscale = fws;                 // 2048
    float* sscale = dscale + 2048;       // 512
    float* smean  = sscale + 512;        // 512
    float* cscale = smean + 512;         // 512
    float* predv  = cscale + 512;        // 512
    float* diffs  = predv + 512;         // 512
    float* corrb  = diffs + 512;         // 32
    unsigned short* docB  = (unsigned short*)(corrb + 32);
    unsigned short* segB  = docB + (size_t)2048 * 768;
    unsigned short* W1T   = segB + (size_t)512 * 768;     // [768][1536]
    unsigned short* W2T   = W1T + (size_t)768 * 1536;     // [384][768]
    unsigned short* XdocB = W2T + (size_t)384 * 768;      // [2048][768]
    unsigned short* XsegB = XdocB + (size_t)2048 * 768;   // [512][768]

    k_norms<<<2560, 64, 0, stream>>>(doc, seg, dscale, sscale, smean, cscale, docB, segB);
    k_transpose_cvt<<<dim3(12, 24), 256, 0, stream>>>(W1, W1T, 1536, 768);
    k_transpose_cvt<<<dim3(6, 12), 256, 0, stream>>>(W2, W2T, 768, 384);
    k_l1<<<dim3(40, 6), 256, 0, stream>>>(docB, segB, W1T, b1, XdocB, XsegB);
    k_fused_mfma<<<512, 256, 0, stream>>>(XdocB, XsegB, W2T, b2, W3, b3, nd, ns,
                                          out + 544, predv);
    k_cos_mfma<<<32, 256, 0, stream>>>(docB, segB, dscale, sscale, nd, ns, predv, diffs);
    k_corr<<<32, 256, 0, stream>>>(seg, smean, cscale, ns, predv, corrb);
    k_final<<<1, 256, 0, stream>>>(tagg, tis, ns, diffs, corrb, out);
}